// Round 1
// baseline (1952.607 us; speedup 1.0000x reference)
//
#include <hip/hip_runtime.h>
#include <math.h>

#define TT 4096
#define AA 4
#define NN 16384
#define QBQ 32
#define KBK 128
#define SS 512
#define HH 4
#define DKD 32
#define CAC 128
#define CPC 16
#define CTC 384

#define EPI_PLAIN 0
#define EPI_SIG   1
#define EPI_ADA   2
#define EPI_RELU  3

__device__ __forceinline__ float sig_(float x) { return 1.0f / (1.0f + __expf(-x)); }

// ---------------------------------------------------------------------------
// K1: per-atom conditioning: act (=qsc, init qact), qn = LN(act) (unweighted),
//     rq = relu(act)@w_s2p_row, rk = relu(act)@w_s2p_col
// ---------------------------------------------------------------------------
__global__ __launch_bounds__(128) void k_atom_cond(
    const float* __restrict__ pos, const float* __restrict__ msk,
    const int* __restrict__ elem, const float* __restrict__ chg,
    const int* __restrict__ chars,
    const float* __restrict__ w_pos, const float* __restrict__ w_msk,
    const float* __restrict__ w_elem, const float* __restrict__ w_chg,
    const float* __restrict__ w_name,
    const float* __restrict__ w_row, const float* __restrict__ w_col,
    float* __restrict__ qsc, float* __restrict__ qact, float* __restrict__ qn,
    float* __restrict__ rq, float* __restrict__ rk)
{
    const int n = blockIdx.x, c = threadIdx.x;
    const float p0 = pos[n*3+0], p1 = pos[n*3+1], p2 = pos[n*3+2];
    const float m = msk[n];
    const int   el = elem[n];
    const float ach = asinhf(chg[n]);
    const int c0 = chars[n*4+0], c1 = chars[n*4+1], c2 = chars[n*4+2], c3 = chars[n*4+3];

    float a = p0*w_pos[c] + p1*w_pos[CAC+c] + p2*w_pos[2*CAC+c]
            + m*w_msk[c] + w_elem[el*CAC+c] + ach*w_chg[c]
            + w_name[(c0      )*CAC+c] + w_name[( 64+c1)*CAC+c]
            + w_name[(128+c2)*CAC+c] + w_name[(192+c3)*CAC+c];
    a *= m;

    const size_t base = (size_t)n*CAC + c;
    qsc[base] = a; qact[base] = a;

    __shared__ float red[128];
    __shared__ float sh[128];
    red[c] = a; __syncthreads();
    for (int off = 64; off > 0; off >>= 1) { if (c < off) red[c] += red[c+off]; __syncthreads(); }
    const float mu = red[0] * (1.0f/128.0f);
    __syncthreads();
    const float d = a - mu;
    red[c] = d*d; __syncthreads();
    for (int off = 64; off > 0; off >>= 1) { if (c < off) red[c] += red[c+off]; __syncthreads(); }
    const float var = red[0] * (1.0f/128.0f);
    qn[base] = d * rsqrtf(var + 1e-5f);
    __syncthreads();
    sh[c] = fmaxf(a, 0.0f);
    __syncthreads();
    if (c < 32) {
        const float* w = (c < 16) ? w_row : w_col;
        const int cc = c & 15;
        float acc = 0.0f;
        #pragma unroll 8
        for (int r = 0; r < 128; ++r) acc += sh[r] * w[r*CPC + cc];
        if (c < 16) rq[(size_t)n*CPC + cc] = acc;
        else        rk[(size_t)n*CPC + cc] = acc;
    }
}

// ---------------------------------------------------------------------------
// K2: pair conditioning + 3-layer MLP residual; one thread per (s,q,k)
// ---------------------------------------------------------------------------
__global__ __launch_bounds__(256) void k_pair(
    const float* __restrict__ pos, const int* __restrict__ uid,
    const float* __restrict__ rq, const float* __restrict__ rk,
    const float* __restrict__ w_ofs, const float* __restrict__ w_dist,
    const float* __restrict__ w_pm,
    const float* __restrict__ mlp1, const float* __restrict__ mlp2,
    const float* __restrict__ mlp3,
    float* __restrict__ pair)
{
    __shared__ float sm1[256], sm2[256], sm3[256], sofs[48], sdist[16], smask[16];
    const int tid = threadIdx.x;
    sm1[tid] = mlp1[tid]; sm2[tid] = mlp2[tid]; sm3[tid] = mlp3[tid];
    if (tid < 48) sofs[tid] = w_ofs[tid];
    if (tid < 16) { sdist[tid] = w_dist[tid]; smask[tid] = w_pm[tid]; }
    __syncthreads();

    const int gid = blockIdx.x*256 + tid;
    const int s = gid >> 12;
    const int rem = gid & 4095;
    const int q = rem >> 7, kk = rem & 127;
    const int n = s*QBQ + q;
    int kidx = s*QBQ - 48 + kk; kidx = max(0, min(NN-1, kidx));

    const float v = (uid[n] == uid[kidx]) ? 1.0f : 0.0f;
    const float o0 = pos[n*3+0]-pos[kidx*3+0];
    const float o1 = pos[n*3+1]-pos[kidx*3+1];
    const float o2 = pos[n*3+2]-pos[kidx*3+2];
    const float sq = o0*o0 + o1*o1 + o2*o2;
    const float inv = 1.0f/(1.0f + sq);

    const float* rqp = rq + (size_t)n*CPC;
    const float* rkp = rk + (size_t)kidx*CPC;

    float p[16], t1[16], t2[16];
    #pragma unroll
    for (int j = 0; j < 16; ++j)
        p[j] = v*(o0*sofs[j] + o1*sofs[16+j] + o2*sofs[32+j] + inv*sdist[j] + smask[j])
             + rqp[j] + rkp[j];
    #pragma unroll
    for (int j = 0; j < 16; ++j) {
        float acc = 0.0f;
        #pragma unroll
        for (int r = 0; r < 16; ++r) acc += fmaxf(p[r], 0.0f) * sm1[r*16+j];
        t1[j] = acc;
    }
    #pragma unroll
    for (int j = 0; j < 16; ++j) {
        float acc = 0.0f;
        #pragma unroll
        for (int r = 0; r < 16; ++r) acc += fmaxf(t1[r], 0.0f) * sm2[r*16+j];
        t2[j] = acc;
    }
    #pragma unroll
    for (int j = 0; j < 16; ++j) {
        float acc = 0.0f;
        #pragma unroll
        for (int r = 0; r < 16; ++r) acc += fmaxf(t2[r], 0.0f) * sm3[r*16+j];
        t1[j] = p[j] + acc;
    }
    float* op = pair + (size_t)gid*CPC;
    #pragma unroll
    for (int j = 0; j < 4; ++j)
        *(float4*)(op + j*4) = make_float4(t1[j*4], t1[j*4+1], t1[j*4+2], t1[j*4+3]);
}

// ---------------------------------------------------------------------------
// K3: row LayerNorm (unweighted) of a [N,128] tensor
// ---------------------------------------------------------------------------
__global__ __launch_bounds__(128) void k_rowln(const float* __restrict__ x, float* __restrict__ y)
{
    const int n = blockIdx.x, c = threadIdx.x;
    __shared__ float red[128];
    const float v = x[(size_t)n*CAC + c];
    red[c] = v; __syncthreads();
    for (int off = 64; off > 0; off >>= 1) { if (c < off) red[c] += red[c+off]; __syncthreads(); }
    const float mu = red[0] * (1.0f/128.0f);
    __syncthreads();
    const float d = v - mu;
    red[c] = d*d; __syncthreads();
    for (int off = 64; off > 0; off >>= 1) { if (c < off) red[c] += red[c+off]; __syncthreads(); }
    const float var = red[0] * (1.0f/128.0f);
    y[(size_t)n*CAC + c] = d * rsqrtf(var + 1e-5f);
}

// ---------------------------------------------------------------------------
// K4: generic fp32 tiled GEMM  out[M,NC] = A[M,K] @ B[K,NC]  (+ epilogues)
//     64x128 tile, BK=32, 4x8 micro-tile, 256 threads
// ---------------------------------------------------------------------------
template<int EPI, bool DUAL, bool ASCALE, bool AMUL>
__global__ __launch_bounds__(256) void k_gemm(
    const float* __restrict__ A, const float* __restrict__ A2,
    const float* __restrict__ asc,
    const float* __restrict__ B1, const float* __restrict__ B2,
    const float* __restrict__ bias, const float* __restrict__ extra,
    float* __restrict__ out, int M, int K, int NC)
{
    __shared__ float As[32][68];
    __shared__ float Bs1[32][128];
    __shared__ float Bs2[DUAL ? 32 : 1][128];

    const int tid = threadIdx.x;
    const int row0 = blockIdx.x * 64;
    const int col0 = blockIdx.y * 128;
    const int m0 = (tid >> 4) * 4;
    const int c0 = (tid & 15) * 8;

    float acc1[4][8];
    float acc2[DUAL ? 4 : 1][DUAL ? 8 : 1];
    #pragma unroll
    for (int i = 0; i < 4; ++i)
        #pragma unroll
        for (int j = 0; j < 8; ++j) acc1[i][j] = 0.0f;
    if constexpr (DUAL) {
        #pragma unroll
        for (int i = 0; i < 4; ++i)
            #pragma unroll
            for (int j = 0; j < 8; ++j) acc2[i][j] = 0.0f;
    }

    for (int k0 = 0; k0 < K; k0 += 32) {
        #pragma unroll
        for (int j = 0; j < 2; ++j) {
            const int idx = tid + j*256;
            const int ar = idx >> 3;
            const int a4 = (idx & 7) * 4;
            const float4 av4 = *(const float4*)(A + (size_t)(row0+ar)*K + k0 + a4);
            float av[4] = {av4.x, av4.y, av4.z, av4.w};
            if constexpr (AMUL) {
                const float4 m4 = *(const float4*)(A2 + (size_t)(row0+ar)*K + k0 + a4);
                av[0]*=m4.x; av[1]*=m4.y; av[2]*=m4.z; av[3]*=m4.w;
            }
            if constexpr (ASCALE) {
                const float4 s4 = *(const float4*)(asc + k0 + a4);
                av[0]*=s4.x; av[1]*=s4.y; av[2]*=s4.z; av[3]*=s4.w;
            }
            As[a4+0][ar]=av[0]; As[a4+1][ar]=av[1]; As[a4+2][ar]=av[2]; As[a4+3][ar]=av[3];
        }
        #pragma unroll
        for (int j = 0; j < 4; ++j) {
            const int idx = tid + j*256;
            const int bk = idx >> 5;
            const int cc = (idx & 31) * 4;
            *(float4*)&Bs1[bk][cc] = *(const float4*)(B1 + (size_t)(k0+bk)*NC + col0 + cc);
            if constexpr (DUAL)
                *(float4*)&Bs2[bk][cc] = *(const float4*)(B2 + (size_t)(k0+bk)*NC + col0 + cc);
        }
        __syncthreads();
        #pragma unroll
        for (int k = 0; k < 32; ++k) {
            const float4 a4 = *(const float4*)&As[k][m0];
            const float4 b04 = *(const float4*)&Bs1[k][c0];
            const float4 b14 = *(const float4*)&Bs1[k][c0+4];
            const float a[4] = {a4.x, a4.y, a4.z, a4.w};
            const float b[8] = {b04.x,b04.y,b04.z,b04.w,b14.x,b14.y,b14.z,b14.w};
            #pragma unroll
            for (int i = 0; i < 4; ++i)
                #pragma unroll
                for (int j = 0; j < 8; ++j)
                    acc1[i][j] = fmaf(a[i], b[j], acc1[i][j]);
            if constexpr (DUAL) {
                const float4 d04 = *(const float4*)&Bs2[k][c0];
                const float4 d14 = *(const float4*)&Bs2[k][c0+4];
                const float bb[8] = {d04.x,d04.y,d04.z,d04.w,d14.x,d14.y,d14.z,d14.w};
                #pragma unroll
                for (int i = 0; i < 4; ++i)
                    #pragma unroll
                    for (int j = 0; j < 8; ++j)
                        acc2[i][j] = fmaf(a[i], bb[j], acc2[i][j]);
            }
        }
        __syncthreads();
    }

    #pragma unroll
    for (int i = 0; i < 4; ++i) {
        const int row = row0 + m0 + i;
        float vb[8];
        #pragma unroll
        for (int j = 0; j < 8; ++j) {
            const int col = col0 + c0 + j;
            float v = acc1[i][j];
            if constexpr (EPI == EPI_PLAIN) {
                if (bias) v += bias[col];
            } else if constexpr (EPI == EPI_SIG) {
                if (bias) v += bias[col];
                v = sig_(v);
            } else if constexpr (EPI == EPI_RELU) {
                v = fmaxf(v, 0.0f);
            } else if constexpr (EPI == EPI_ADA) {
                v = sig_(v + bias[col]) * extra[(size_t)row*CAC + col] + acc2[i][j];
            }
            vb[j] = v;
        }
        float* op = out + (size_t)row*NC + col0 + c0;
        *(float4*)(op  ) = make_float4(vb[0],vb[1],vb[2],vb[3]);
        *(float4*)(op+4) = make_float4(vb[4],vb[5],vb[6],vb[7]);
    }
}

// ---------------------------------------------------------------------------
// K5: attention for one subset s (all 4 heads). 64 KB LDS logits buffer,
//     rotation-swizzled access (stride-128 rows would be 32/64-way conflicts).
// ---------------------------------------------------------------------------
__global__ __launch_bounds__(256) void k_attn(
    const float* __restrict__ qh, const float* __restrict__ kh,
    const float* __restrict__ vh, const float* __restrict__ pair,
    const float* __restrict__ wln, const float* __restrict__ wpl,
    int blk, float* __restrict__ oh)
{
    __shared__ float L[4*32*128];   // [h][q][kb], exactly 64 KB
    const int s = blockIdx.x, tid = threadIdx.x;
    const int n0 = s*QBQ;
    const int kbase = n0 - 48;
    const float SCALE = 0.17677669529663687f; // 32^-0.5

    // --- pair -> per-block logits (LN over 16 + 4-wide projection) ---
    for (int idx = tid; idx < QBQ*KBK; idx += 256) {
        const int q = idx >> 7, kk = idx & 127;
        const float* pp = pair + ((size_t)(n0+q)*KBK + kk)*CPC;
        float p[16];
        #pragma unroll
        for (int j = 0; j < 4; ++j) {
            const float4 v4 = *(const float4*)(pp + j*4);
            p[j*4]=v4.x; p[j*4+1]=v4.y; p[j*4+2]=v4.z; p[j*4+3]=v4.w;
        }
        float sm = 0.0f;
        #pragma unroll
        for (int j = 0; j < 16; ++j) sm += p[j];
        const float mu = sm * (1.0f/16.0f);
        float sq = 0.0f;
        #pragma unroll
        for (int j = 0; j < 16; ++j) { const float d = p[j]-mu; sq += d*d; }
        const float rs = rsqrtf(sq*(1.0f/16.0f) + 1e-5f);
        float l[4] = {0,0,0,0};
        #pragma unroll
        for (int j = 0; j < 16; ++j) {
            const float xn = (p[j]-mu)*rs*wln[j];
            const float* wr = wpl + j*12 + blk*4;
            l[0] += xn*wr[0]; l[1] += xn*wr[1]; l[2] += xn*wr[2]; l[3] += xn*wr[3];
        }
        #pragma unroll
        for (int h = 0; h < 4; ++h) L[(h*32+q)*128 + kk] = l[h];
    }
    __syncthreads();

    // --- logits += (q*scale) . k ---
    {
        const int hq = tid >> 1, half = tid & 1;
        const int h = hq >> 5, q = hq & 31;
        float qr[32];
        const float* qp = qh + (size_t)(n0+q)*CAC + h*DKD;
        #pragma unroll
        for (int j = 0; j < 8; ++j) {
            const float4 v4 = *(const float4*)(qp + j*4);
            qr[j*4]=v4.x*SCALE; qr[j*4+1]=v4.y*SCALE; qr[j*4+2]=v4.z*SCALE; qr[j*4+3]=v4.w*SCALE;
        }
        const int kb0 = half*64;
        for (int kbl = 0; kbl < 64; ++kbl) {
            const int kb = kb0 + ((kbl + hq) & 63);
            int kidx = kbase + kb; kidx = max(0, min(NN-1, kidx));
            const float* kp = kh + (size_t)kidx*CAC + h*DKD;
            float acc = 0.0f;
            #pragma unroll
            for (int j = 0; j < 8; ++j) {
                const float4 kv = *(const float4*)(kp + j*4);
                acc += qr[j*4]*kv.x + qr[j*4+1]*kv.y + qr[j*4+2]*kv.z + qr[j*4+3]*kv.w;
            }
            L[(h*32+q)*128 + kb] += acc;
        }
    }
    __syncthreads();

    // --- softmax per (h,q) row ---
    if (tid < 128) {
        float* row = &L[tid*128];
        float mx = -3.0e38f;
        for (int kbl = 0; kbl < 128; ++kbl) { const int kb = (kbl + tid) & 127; mx = fmaxf(mx, row[kb]); }
        float sum = 0.0f;
        for (int kbl = 0; kbl < 128; ++kbl) {
            const int kb = (kbl + tid) & 127;
            const float e = __expf(row[kb]-mx); row[kb] = e; sum += e;
        }
        const float inv = 1.0f / sum;
        for (int kbl = 0; kbl < 128; ++kbl) { const int kb = (kbl + tid) & 127; row[kb] *= inv; }
    }
    __syncthreads();

    // --- o = aw @ v ---
    {
        const int q = tid >> 3, h = (tid >> 1) & 3, dh = tid & 1;
        float o[16];
        #pragma unroll
        for (int j = 0; j < 16; ++j) o[j] = 0.0f;
        const float* lrow = &L[(h*32+q)*128];
        for (int kbl = 0; kbl < 128; ++kbl) {
            const int kb = (kbl + tid) & 127;
            const float aw = lrow[kb];
            int kidx = kbase + kb; kidx = max(0, min(NN-1, kidx));
            const float* vp = vh + (size_t)kidx*CAC + h*DKD + dh*16;
            #pragma unroll
            for (int j = 0; j < 4; ++j) {
                const float4 vv = *(const float4*)(vp + j*4);
                o[j*4]   = fmaf(aw, vv.x, o[j*4]);
                o[j*4+1] = fmaf(aw, vv.y, o[j*4+1]);
                o[j*4+2] = fmaf(aw, vv.z, o[j*4+2]);
                o[j*4+3] = fmaf(aw, vv.w, o[j*4+3]);
            }
        }
        float* op = oh + (size_t)(n0+q)*CAC + h*DKD + dh*16;
        #pragma unroll
        for (int j = 0; j < 4; ++j)
            *(float4*)(op + j*4) = make_float4(o[j*4], o[j*4+1], o[j*4+2], o[j*4+3]);
    }
}

// ---------------------------------------------------------------------------
// small elementwise kernels
// ---------------------------------------------------------------------------
__global__ __launch_bounds__(256) void k_axpy_mul(float4* __restrict__ y,
    const float4* __restrict__ a, const float4* __restrict__ b)
{
    const int i = blockIdx.x*256 + threadIdx.x;
    float4 yv = y[i]; const float4 av = a[i], bv = b[i];
    yv.x += av.x*bv.x; yv.y += av.y*bv.y; yv.z += av.z*bv.z; yv.w += av.w*bv.w;
    y[i] = yv;
}

__global__ __launch_bounds__(256) void k_silu_mul(float4* __restrict__ h1,
    const float4* __restrict__ h2)
{
    const int i = blockIdx.x*256 + threadIdx.x;
    float4 a = h1[i]; const float4 b = h2[i];
    a.x = a.x * sig_(a.x) * b.x;
    a.y = a.y * sig_(a.y) * b.y;
    a.z = a.z * sig_(a.z) * b.z;
    a.w = a.w * sig_(a.w) * b.w;
    h1[i] = a;
}

__global__ __launch_bounds__(256) void k_token_reduce(
    const float* __restrict__ tok, const float* __restrict__ msk, float* __restrict__ out)
{
    const int gid = blockIdx.x*256 + threadIdx.x;   // T*CT
    const int t = gid / CTC, c = gid - t*CTC;
    float num = 0.0f, den = 0.0f;
    #pragma unroll
    for (int a = 0; a < AA; ++a) {
        const float mv = msk[t*AA + a];
        num += tok[(size_t)(t*AA+a)*CTC + c] * mv;
        den += mv;
    }
    out[gid] = num / fmaxf(den, 1e-10f);
}

// ---------------------------------------------------------------------------
// launch
// ---------------------------------------------------------------------------
extern "C" void kernel_launch(void* const* d_in, const int* in_sizes, int n_in,
                              void* d_out, int out_size, void* d_ws, size_t ws_size,
                              hipStream_t stream)
{
    const float* positions = (const float*)d_in[0];
    const float* maskp     = (const float*)d_in[1];
    const int*   element   = (const int*  )d_in[2];
    const float* charge    = (const float*)d_in[3];
    const int*   chars     = (const int*  )d_in[4];
    const int*   uid       = (const int*  )d_in[5];
    const float* w_ref_pos      = (const float*)d_in[6];
    const float* w_ref_mask     = (const float*)d_in[7];
    const float* w_ref_element  = (const float*)d_in[8];
    const float* w_ref_charge   = (const float*)d_in[9];
    const float* w_ref_atom_name= (const float*)d_in[10];
    const float* w_s2p_row      = (const float*)d_in[11];
    const float* w_s2p_col      = (const float*)d_in[12];
    const float* w_pair_offsets = (const float*)d_in[13];
    const float* w_pair_dist    = (const float*)d_in[14];
    const float* w_pair_mask    = (const float*)d_in[15];
    const float* w_pair_mlp1    = (const float*)d_in[16];
    const float* w_pair_mlp2    = (const float*)d_in[17];
    const float* w_pair_mlp3    = (const float*)d_in[18];
    const float* w_pair_ln      = (const float*)d_in[19];
    const float* w_pair_logits  = (const float*)d_in[20];
    const float* aq_lnw = (const float*)d_in[21];
    const float* aq_gw  = (const float*)d_in[22];
    const float* aq_gb  = (const float*)d_in[23];
    const float* aq_sw  = (const float*)d_in[24];
    const float* ak_lnw = (const float*)d_in[25];
    const float* ak_gw  = (const float*)d_in[26];
    const float* ak_gb  = (const float*)d_in[27];
    const float* ak_sw  = (const float*)d_in[28];
    const float* wq     = (const float*)d_in[29];
    const float* bq     = (const float*)d_in[30];
    const float* wk     = (const float*)d_in[31];
    const float* wv     = (const float*)d_in[32];
    const float* wg     = (const float*)d_in[33];
    const float* azi_w  = (const float*)d_in[34];
    const float* azi_cw = (const float*)d_in[35];
    const float* azi_cb = (const float*)d_in[36];
    const float* t_lnw  = (const float*)d_in[37];
    const float* t_gw   = (const float*)d_in[38];
    const float* t_gb   = (const float*)d_in[39];
    const float* t_sw   = (const float*)d_in[40];
    const float* glu1   = (const float*)d_in[41];
    const float* glu2   = (const float*)d_in[42];
    const float* t_azi_w  = (const float*)d_in[43];
    const float* t_azi_cw = (const float*)d_in[44];
    const float* t_azi_cb = (const float*)d_in[45];
    const float* w_project= (const float*)d_in[46];

    float* token_o = (float*)d_out;
    float* qact = token_o + 1572864;         // N*CA
    float* qsc  = token_o + 3670016;
    float* pair = token_o + 5767168;         // S*QB*KB*CP

    float* ws = (float*)d_ws;
    const size_t M2 = 2097152;               // N*CA
    float* w_qn = ws;                        // 2M
    float* w_qa = ws + M2;                   // 2M
    float* w_rq = ws + 2*M2;                 // 256K
    float* w_rk = ws + 2*M2 + 262144;        // 256K
    float* w_xq = ws + 2*M2 + 524288;        // 2M
    float* w_xk = w_xq + M2;                 // 2M
    float* w_q  = w_xk + M2;                 // 2M
    float* w_k  = w_q  + M2;                 // 2M
    float* w_v  = w_k  + M2;                 // 2M
    float* w_g  = w_v  + M2;                 // 2M
    float* w_o  = w_g  + M2;                 // 2M  (total 19398656 floats = 74 MB)
    float* w_h1 = w_q;                       // alias: N*256 over q+k
    float* w_h2 = w_v;                       // alias: N*256 over v+g
    float* w_tok= w_q;                       // alias: N*384

    (void)in_sizes; (void)n_in; (void)out_size; (void)ws_size;

    const dim3 blk128(128), blk256(256);
    const dim3 g128(NN/64, 1), g256c(NN/64, 2), g384c(NN/64, 3);

    k_atom_cond<<<NN, blk128, 0, stream>>>(positions, maskp, element, charge, chars,
        w_ref_pos, w_ref_mask, w_ref_element, w_ref_charge, w_ref_atom_name,
        w_s2p_row, w_s2p_col, qsc, qact, w_qn, w_rq, w_rk);

    k_pair<<<(SS*QBQ*KBK)/256, blk256, 0, stream>>>(positions, uid, w_rq, w_rk,
        w_pair_offsets, w_pair_dist, w_pair_mask, w_pair_mlp1, w_pair_mlp2, w_pair_mlp3, pair);

    for (int i = 0; i < 3; ++i) {
        const size_t oM = (size_t)i*CAC*CAC;
        const size_t oV = (size_t)i*CAC;
        const size_t oG = (size_t)i*CAC*2*CAC;

        k_rowln<<<NN, blk128, 0, stream>>>(qact, w_qa);
        // xq / xk (adaLN, dual-B)
        k_gemm<EPI_ADA,true,true,false><<<g128, blk256, 0, stream>>>(
            w_qn, nullptr, aq_lnw+oV, aq_gw+oM, aq_sw+oM, aq_gb+oV, w_qa, w_xq, NN, CAC, CAC);
        k_gemm<EPI_ADA,true,true,false><<<g128, blk256, 0, stream>>>(
            w_qn, nullptr, ak_lnw+oV, ak_gw+oM, ak_sw+oM, ak_gb+oV, w_qa, w_xk, NN, CAC, CAC);
        // projections
        k_gemm<EPI_PLAIN,false,false,false><<<g128, blk256, 0, stream>>>(
            w_xq, nullptr, nullptr, wq+oM, nullptr, bq+oV, nullptr, w_q, NN, CAC, CAC);
        k_gemm<EPI_PLAIN,false,false,false><<<g128, blk256, 0, stream>>>(
            w_xk, nullptr, nullptr, wk+oM, nullptr, nullptr, nullptr, w_k, NN, CAC, CAC);
        k_gemm<EPI_PLAIN,false,false,false><<<g128, blk256, 0, stream>>>(
            w_xk, nullptr, nullptr, wv+oM, nullptr, nullptr, nullptr, w_v, NN, CAC, CAC);
        k_gemm<EPI_SIG,false,false,false><<<g128, blk256, 0, stream>>>(
            w_xq, nullptr, nullptr, wg+oM, nullptr, nullptr, nullptr, w_g, NN, CAC, CAC);
        // attention
        k_attn<<<SS, blk256, 0, stream>>>(w_q, w_k, w_v, pair, w_pair_ln, w_pair_logits, i, w_o);
        // o-projection with adaptive zero-init gate
        k_gemm<EPI_PLAIN,false,false,true><<<g128, blk256, 0, stream>>>(
            w_o, w_g, nullptr, azi_w+oM, nullptr, nullptr, nullptr, w_xq, NN, CAC, CAC);
        k_gemm<EPI_SIG,false,false,false><<<g128, blk256, 0, stream>>>(
            qsc, nullptr, nullptr, azi_cw+oM, nullptr, azi_cb+oV, nullptr, w_xk, NN, CAC, CAC);
        k_axpy_mul<<<2048, blk256, 0, stream>>>((float4*)qact, (const float4*)w_xq, (const float4*)w_xk);
        // transition
        k_rowln<<<NN, blk128, 0, stream>>>(qact, w_qa);
        k_gemm<EPI_ADA,true,true,false><<<g128, blk256, 0, stream>>>(
            w_qn, nullptr, t_lnw+oV, t_gw+oM, t_sw+oM, t_gb+oV, w_qa, w_xq, NN, CAC, CAC);
        k_gemm<EPI_PLAIN,false,false,false><<<g256c, blk256, 0, stream>>>(
            w_xq, nullptr, nullptr, glu1+oG, nullptr, nullptr, nullptr, w_h1, NN, CAC, 2*CAC);
        k_gemm<EPI_PLAIN,false,false,false><<<g256c, blk256, 0, stream>>>(
            w_xq, nullptr, nullptr, glu2+oG, nullptr, nullptr, nullptr, w_h2, NN, CAC, 2*CAC);
        k_silu_mul<<<4096, blk256, 0, stream>>>((float4*)w_h1, (const float4*)w_h2);
        k_gemm<EPI_PLAIN,false,false,false><<<g128, blk256, 0, stream>>>(
            w_h1, nullptr, nullptr, t_azi_w+oG, nullptr, nullptr, nullptr, w_o, NN, 2*CAC, CAC);
        k_gemm<EPI_SIG,false,false,false><<<g128, blk256, 0, stream>>>(
            qsc, nullptr, nullptr, t_azi_cw+oM, nullptr, t_azi_cb+oV, nullptr, w_xk, NN, CAC, CAC);
        k_axpy_mul<<<2048, blk256, 0, stream>>>((float4*)qact, (const float4*)w_o, (const float4*)w_xk);
    }

    // token projection + masked mean over the 4 atoms per token
    k_gemm<EPI_RELU,false,false,false><<<g384c, blk256, 0, stream>>>(
        qact, nullptr, nullptr, w_project, nullptr, nullptr, nullptr, w_tok, NN, CAC, CTC);
    k_token_reduce<<<(TT*CTC)/256, blk256, 0, stream>>>(w_tok, maskp, token_o);
}